// Round 13
// baseline (202.914 us; speedup 1.0000x reference)
//
#include <hip/hip_runtime.h>
#include <hip/hip_cooperative_groups.h>
#include <cstddef>

// Fused-with-fallback: try ONE cooperative dispatch (phase1 = node proj,
// grid.sync, phase2 = edge map); if the driver rejects the cooperative
// launch, fall back to the proven r12 two-kernel path. Both paths run the
// SAME __device__ bodies -> bitwise-identical output, deterministic choice.
//
// out[e,j] = tanh( A[row[e],j] + B[col[e],j] )
// A[n] = W0·u + W1·v,  B[n] = W0·v + W1·u,  u = x[n,0:64]+x[n,128:192], v = x[n,64:128]
// Karatsuba: s=(W0+W1)/2·(u+v), d=(W0-W1)/2·(u-v) => A=s+d, B=s-d.
// A/B: fp16 records padded to 32B; quad-cooperative 8B/lane gathers.

namespace cg = cooperative_groups;

typedef float v4f __attribute__((ext_vector_type(4)));
typedef _Float16 v4h __attribute__((ext_vector_type(4)));

__device__ __forceinline__ float tanh_fast(float s) {
    float ex = __builtin_amdgcn_exp2f(s * 2.88539008f);
    return fmaf(-2.0f, __builtin_amdgcn_rcpf(ex + 1.0f), 1.0f);
}

__device__ __forceinline__ void stage_w(const float* __restrict__ W,
                                        float* ws, float* wd, int tid, int nthr) {
    for (int k = tid; k < 576; k += nthr) {
        int j = k >> 6, c = k & 63;
        float w0 = W[j * 128 + c], w1 = W[j * 128 + 64 + c];
        ws[k] = 0.5f * (w0 + w1);
        wd[k] = 0.5f * (w0 - w1);
    }
}

// One node, computed by a 4-lane quad (this lane holds slice q).
__device__ __forceinline__ void node_body(
    const float* __restrict__ x, const float* ws, const float* wd,
    _Float16* __restrict__ A, _Float16* __restrict__ B, int n, int q)
{
    const float* xr = x + (size_t)n * 192;
    float ps[9], pd[9];
#pragma unroll
    for (int j = 0; j < 9; ++j) { ps[j] = 0.0f; pd[j] = 0.0f; }
#pragma unroll
    for (int ii = 0; ii < 4; ++ii) {
        const int c = 16 * ii + 4 * q;
        v4f x0 = *(const v4f*)(xr + c);
        v4f x1 = *(const v4f*)(xr + 64 + c);
        v4f x2 = *(const v4f*)(xr + 128 + c);
        v4f u = x0 + x2;
        v4f su = u + x1, du = u - x1;
#pragma unroll
        for (int j = 0; j < 9; ++j) {
            v4f a = *(const v4f*)(ws + j * 64 + c);
            v4f b = *(const v4f*)(wd + j * 64 + c);
            ps[j] = fmaf(a.x, su.x, ps[j]); ps[j] = fmaf(a.y, su.y, ps[j]);
            ps[j] = fmaf(a.z, su.z, ps[j]); ps[j] = fmaf(a.w, su.w, ps[j]);
            pd[j] = fmaf(b.x, du.x, pd[j]); pd[j] = fmaf(b.y, du.y, pd[j]);
            pd[j] = fmaf(b.z, du.z, pd[j]); pd[j] = fmaf(b.w, du.w, pd[j]);
        }
    }
#pragma unroll
    for (int j = 0; j < 9; ++j) {
        ps[j] += __shfl_xor(ps[j], 1); ps[j] += __shfl_xor(ps[j], 2);
        pd[j] += __shfl_xor(pd[j], 1); pd[j] += __shfl_xor(pd[j], 2);
    }
    v4h av, bv;                                    // compile-time packed (r12)
    if (q == 0) {
        av[0]=(_Float16)(ps[0]+pd[0]); bv[0]=(_Float16)(ps[0]-pd[0]);
        av[1]=(_Float16)(ps[1]+pd[1]); bv[1]=(_Float16)(ps[1]-pd[1]);
        av[2]=(_Float16)(ps[2]+pd[2]); bv[2]=(_Float16)(ps[2]-pd[2]);
        av[3]=(_Float16)(ps[3]+pd[3]); bv[3]=(_Float16)(ps[3]-pd[3]);
    } else if (q == 1) {
        av[0]=(_Float16)(ps[4]+pd[4]); bv[0]=(_Float16)(ps[4]-pd[4]);
        av[1]=(_Float16)(ps[5]+pd[5]); bv[1]=(_Float16)(ps[5]-pd[5]);
        av[2]=(_Float16)(ps[6]+pd[6]); bv[2]=(_Float16)(ps[6]-pd[6]);
        av[3]=(_Float16)(ps[7]+pd[7]); bv[3]=(_Float16)(ps[7]-pd[7]);
    } else if (q == 2) {
        av[0]=(_Float16)(ps[8]+pd[8]); bv[0]=(_Float16)(ps[8]-pd[8]);
        av[1]=av[2]=av[3]=(_Float16)0.0f; bv[1]=bv[2]=bv[3]=(_Float16)0.0f;
    } else {
        av[0]=av[1]=av[2]=av[3]=(_Float16)0.0f;
        bv[0]=bv[1]=bv[2]=bv[3]=(_Float16)0.0f;
    }
    *(v4h*)(A + (size_t)n * 16 + 4 * q) = av;
    *(v4h*)(B + (size_t)n * 16 + 4 * q) = bv;
}

// Two edges per quad -> 4 independent gathers/lane; results into LDS slots.
__device__ __forceinline__ void edge_pair_body(
    const int* __restrict__ ei, const _Float16* __restrict__ A,
    const _Float16* __restrict__ B, float* so, int nedges,
    int e1, int e2, int quad, int nq, int q)
{
    if (q == 3) return;
    int r1 = ei[e1], c1 = ei[nedges + e1];
    int r2 = ei[e2], c2 = ei[nedges + e2];
    float* s1 = so + quad * 9;
    float* s2 = so + (quad + nq) * 9;
    if (q < 2) {
        v4h a1 = *(const v4h*)(A + (size_t)r1 * 16 + 4 * q);
        v4h b1 = *(const v4h*)(B + (size_t)c1 * 16 + 4 * q);
        v4h a2 = *(const v4h*)(A + (size_t)r2 * 16 + 4 * q);
        v4h b2 = *(const v4h*)(B + (size_t)c2 * 16 + 4 * q);
#pragma unroll
        for (int i = 0; i < 4; ++i) {
            s1[4 * q + i] = tanh_fast((float)a1[i] + (float)b1[i]);
            s2[4 * q + i] = tanh_fast((float)a2[i] + (float)b2[i]);
        }
    } else {                                       // q == 2 -> j = 8
        s1[8] = tanh_fast((float)A[(size_t)r1 * 16 + 8] + (float)B[(size_t)c1 * 16 + 8]);
        s2[8] = tanh_fast((float)A[(size_t)r2 * 16 + 8] + (float)B[(size_t)c2 * 16 + 8]);
    }
}

// ---------------- cooperative fused kernel ----------------
__global__ __launch_bounds__(512, 4) void fused_kernel(
    const float* __restrict__ x, const float* __restrict__ W,
    const int* __restrict__ ei, _Float16* __restrict__ A,
    _Float16* __restrict__ B, float* __restrict__ out,
    int nnodes, int nedges)
{
    __shared__ float smem[2304];                   // 9 KB, overlaid per phase
    float* ws = smem;
    float* wd = smem + 576;
    const int tid = threadIdx.x, quad = tid >> 2, q = tid & 3;   // quad 0..127

    stage_w(W, ws, wd, tid, 512);
    __syncthreads();

    const int nchunk1 = (nnodes + 127) >> 7;       // 128 nodes/chunk
    for (int ch = blockIdx.x; ch < nchunk1; ch += gridDim.x) {
        int n = ch * 128 + quad;
        if (n < nnodes) node_body(x, ws, wd, A, B, n, q);
    }

    __threadfence();                               // publish A/B device-wide
    cg::this_grid().sync();

    float* so = smem;                              // reuse as [256*9]
    const int nchunk2 = (nedges + 255) >> 8;       // 256 edges/chunk
    for (int ch = blockIdx.x; ch < nchunk2; ch += gridDim.x) {
        const int e0 = ch * 256;
        __syncthreads();                           // so reuse guard
        int e1 = min(e0 + quad,       nedges - 1);
        int e2 = min(e0 + 128 + quad, nedges - 1);
        edge_pair_body(ei, A, B, so, nedges, e1, e2, quad, 128, q);
        __syncthreads();
        const int nval = min(256, nedges - e0) * 9;
        float* ob = out + (size_t)e0 * 9;
        for (int k4 = tid * 4; k4 < nval; k4 += 2048) {
            if (k4 + 4 <= nval) *(v4f*)(ob + k4) = *(const v4f*)(so + k4);
            else for (int m = k4; m < nval; ++m) ob[m] = so[m];
        }
    }
}

// ---------------- fallback two-kernel path (r12) ----------------
__global__ __launch_bounds__(256) void node_proj_kernel(
    const float* __restrict__ x, const float* __restrict__ W,
    _Float16* __restrict__ A, _Float16* __restrict__ B, int nnodes)
{
    __shared__ float ws[576], wd[576];
    stage_w(W, ws, wd, threadIdx.x, 256);
    __syncthreads();
    const int quad = threadIdx.x >> 2, q = threadIdx.x & 3;
    const int n = blockIdx.x * 64 + quad;
    if (n >= nnodes) return;
    node_body(x, ws, wd, A, B, n, q);
}

__global__ __launch_bounds__(256) void edge_map_kernel(
    const int* __restrict__ ei, const _Float16* __restrict__ A,
    const _Float16* __restrict__ B, float* __restrict__ out, int nedges)
{
    __shared__ float so[128 * 9];
    const int quad = threadIdx.x >> 2, q = threadIdx.x & 3;
    const int e0 = blockIdx.x * 128;
    int e1 = min(e0 + quad,      nedges - 1);
    int e2 = min(e0 + 64 + quad, nedges - 1);
    edge_pair_body(ei, A, B, so, nedges, e1, e2, quad, 64, q);
    __syncthreads();
    const int nval = min(128, nedges - e0) * 9;
    float* ob = out + (size_t)e0 * 9;
    for (int k4 = threadIdx.x * 4; k4 < nval; k4 += 1024) {
        if (k4 + 4 <= nval) *(v4f*)(ob + k4) = *(const v4f*)(so + k4);
        else for (int m = k4; m < nval; ++m) ob[m] = so[m];
    }
}

extern "C" void kernel_launch(void* const* d_in, const int* in_sizes, int n_in,
                              void* d_out, int out_size, void* d_ws, size_t ws_size,
                              hipStream_t stream) {
    const float* x  = (const float*)d_in[0];   // [N, 192] fp32
    const float* W  = (const float*)d_in[1];   // [9, 128] fp32
    const int*   ei = (const int*)d_in[2];     // [2, E] int32
    float* out = (float*)d_out;                // [E*9] fp32

    int nnodes = in_sizes[0] / 192;
    int nedges = in_sizes[2] / 2;

    _Float16* A = (_Float16*)d_ws;             // [nnodes*16] fp16 padded records
    _Float16* B = A + (size_t)nnodes * 16;     // [nnodes*16]

    void* args[] = { (void*)&x, (void*)&W, (void*)&ei,
                     (void*)&A, (void*)&B, (void*)&out,
                     (void*)&nnodes, (void*)&nedges };

    // 512 blocks x 512 thr = 2 blocks/CU (launch_bounds(512,4): VGPR<=128,
    // 9KB LDS -> co-residency safe). Checked launch; deterministic fallback.
    hipError_t err = hipLaunchCooperativeKernel((const void*)fused_kernel,
                                                dim3(512), dim3(512), args, 0, stream);
    if (err != hipSuccess) {
        (void)hipGetLastError();               // clear sticky error state
        node_proj_kernel<<<(nnodes + 63) / 64, 256, 0, stream>>>(x, W, A, B, nnodes);
        edge_map_kernel<<<(nedges + 127) / 128, 256, 0, stream>>>(ei, A, B, out, nedges);
    }
}

// Round 14
// 38.173 us; speedup vs baseline: 5.3156x; 5.3156x over previous
//
#include <hip/hip_runtime.h>
#include <cstddef>

// out[e,j] = tanh( A[row[e],j] + B[col[e],j] )
// A[n] = W0·u + W1·v,  B[n] = W0·v + W1·u,  u = x[n,0:64]+x[n,128:192], v = x[n,64:128]
// Karatsuba: s=(W0+W1)/2·(u+v), d=(W0-W1)/2·(u-v) => A=s+d, B=s-d.
// A/B: fp16 records padded to 32B (16 halves).
//
// r14: ZERO-LDS versions of both kernels (LDS pipe was the modeled excess):
//  k1: 16 lanes/node, W in registers, reduction via pure-DPP ring sum
//      (quad_perm xor1/xor2 + row_ror:4 + row_ror:8 -> full 16-lane sum, VALU only).
//  k2: r12 gather structure, but direct scalar stores (no LDS transpose).

typedef float v4f __attribute__((ext_vector_type(4)));
typedef _Float16 v4h __attribute__((ext_vector_type(4)));

__device__ __forceinline__ float tanh_fast(float s) {
    // tanh(s) = 1 - 2/(e^{2s}+1); exp via exp2. Inf/0 limits give +-1, no clamp.
    float ex = __builtin_amdgcn_exp2f(s * 2.88539008f);
    return fmaf(-2.0f, __builtin_amdgcn_rcpf(ex + 1.0f), 1.0f);
}

// v += v[src-lane] per DPP ctrl. 0xB1=quad_perm[1,0,3,2] (xor1),
// 0x4E=quad_perm[2,3,0,1] (xor2), 0x124=row_ror:4, 0x128=row_ror:8.
// After xor1,xor2 (quad sums) + ror4 + ror8: every lane of each 16-row holds
// the full 16-lane sum (ring reduction; rows never cross node boundaries).
template <int CTRL>
__device__ __forceinline__ float dpp_sum_step(float v) {
    int r = __builtin_amdgcn_mov_dpp(__float_as_int(v), CTRL, 0xF, 0xF, 1);
    return v + __int_as_float(r);
}

// Kernel 1: 16 lanes per node; 16 nodes per 256-thread block. No LDS at all.
__global__ __launch_bounds__(256) void node_proj_kernel(
    const float* __restrict__ x, const float* __restrict__ W,
    _Float16* __restrict__ A, _Float16* __restrict__ B, int nnodes)
{
    const int l16 = threadIdx.x & 15;             // lane within node group
    const int n   = blockIdx.x * 16 + (threadIdx.x >> 4);
    const int c   = 4 * l16;                      // this lane's 4 channels

    // Stage W in registers: 18 x v4f (L1/L2-broadcast reads, per block ~9KB)
    v4f wsr[9], wdr[9];
#pragma unroll
    for (int j = 0; j < 9; ++j) {
        v4f w0 = *(const v4f*)(W + j * 128 + c);
        v4f w1 = *(const v4f*)(W + j * 128 + 64 + c);
        wsr[j] = 0.5f * (w0 + w1);
        wdr[j] = 0.5f * (w0 - w1);
    }

    if (n >= nnodes) return;                      // whole 16-group exits together

    const float* xr = x + (size_t)n * 192;
    v4f x0 = *(const v4f*)(xr + c);               // 256B contiguous per 16-row
    v4f x1 = *(const v4f*)(xr + 64 + c);
    v4f x2 = *(const v4f*)(xr + 128 + c);
    v4f u  = x0 + x2;
    v4f su = u + x1, du = u - x1;

    float ps[9], pd[9];
#pragma unroll
    for (int j = 0; j < 9; ++j) {
        float a;
        a = wsr[j].x * su.x;           a = fmaf(wsr[j].y, su.y, a);
        a = fmaf(wsr[j].z, su.z, a);   a = fmaf(wsr[j].w, su.w, a);
        ps[j] = a;
        float b;
        b = wdr[j].x * du.x;           b = fmaf(wdr[j].y, du.y, b);
        b = fmaf(wdr[j].z, du.z, b);   b = fmaf(wdr[j].w, du.w, b);
        pd[j] = b;
    }

    // 16-lane reduction, pure DPP (VALU pipe only, no LDS)
#pragma unroll
    for (int j = 0; j < 9; ++j) {
        ps[j] = dpp_sum_step<0xB1>(ps[j]);
        ps[j] = dpp_sum_step<0x4E>(ps[j]);
        ps[j] = dpp_sum_step<0x124>(ps[j]);
        ps[j] = dpp_sum_step<0x128>(ps[j]);
        pd[j] = dpp_sum_step<0xB1>(pd[j]);
        pd[j] = dpp_sum_step<0x4E>(pd[j]);
        pd[j] = dpp_sum_step<0x124>(pd[j]);
        pd[j] = dpp_sum_step<0x128>(pd[j]);
    }

    // lanes 0..3 of each 16-group store the packed 32B records (r12 packing)
    if (l16 < 4) {
        const int q = l16;
        v4h av, bv;
        if (q == 0) {
            av[0]=(_Float16)(ps[0]+pd[0]); bv[0]=(_Float16)(ps[0]-pd[0]);
            av[1]=(_Float16)(ps[1]+pd[1]); bv[1]=(_Float16)(ps[1]-pd[1]);
            av[2]=(_Float16)(ps[2]+pd[2]); bv[2]=(_Float16)(ps[2]-pd[2]);
            av[3]=(_Float16)(ps[3]+pd[3]); bv[3]=(_Float16)(ps[3]-pd[3]);
        } else if (q == 1) {
            av[0]=(_Float16)(ps[4]+pd[4]); bv[0]=(_Float16)(ps[4]-pd[4]);
            av[1]=(_Float16)(ps[5]+pd[5]); bv[1]=(_Float16)(ps[5]-pd[5]);
            av[2]=(_Float16)(ps[6]+pd[6]); bv[2]=(_Float16)(ps[6]-pd[6]);
            av[3]=(_Float16)(ps[7]+pd[7]); bv[3]=(_Float16)(ps[7]-pd[7]);
        } else if (q == 2) {
            av[0]=(_Float16)(ps[8]+pd[8]); bv[0]=(_Float16)(ps[8]-pd[8]);
            av[1]=av[2]=av[3]=(_Float16)0.0f; bv[1]=bv[2]=bv[3]=(_Float16)0.0f;
        } else {
            av[0]=av[1]=av[2]=av[3]=(_Float16)0.0f;
            bv[0]=bv[1]=bv[2]=bv[3]=(_Float16)0.0f;
        }
        *(v4h*)(A + (size_t)n * 16 + 4 * q) = av;
        *(v4h*)(B + (size_t)n * 16 + 4 * q) = bv;
    }
}

// Kernel 2: 128 edges per 256-thread block, two edges per quad (4 independent
// gathers/lane), DIRECT scalar stores (no LDS transpose, no __syncthreads).
// Clamped tail edges produce duplicate same-value stores: benign/deterministic.
__global__ __launch_bounds__(256) void edge_map_kernel(
    const int* __restrict__ ei, const _Float16* __restrict__ A,
    const _Float16* __restrict__ B, float* __restrict__ out, int nedges)
{
    const int quad = threadIdx.x >> 2;            // 0..63
    const int q    = threadIdx.x & 3;
    const int e0   = blockIdx.x * 128;
    if (q == 3) return;                           // pad halves only

    const int e1 = min(e0 + quad,      nedges - 1);
    const int e2 = min(e0 + 64 + quad, nedges - 1);
    int r1 = ei[e1], c1 = ei[nedges + e1];        // quad-broadcast loads
    int r2 = ei[e2], c2 = ei[nedges + e2];

    if (q < 2) {
        v4h a1 = *(const v4h*)(A + (size_t)r1 * 16 + 4 * q);
        v4h b1 = *(const v4h*)(B + (size_t)c1 * 16 + 4 * q);
        v4h a2 = *(const v4h*)(A + (size_t)r2 * 16 + 4 * q);
        v4h b2 = *(const v4h*)(B + (size_t)c2 * 16 + 4 * q);
        float* o1 = out + (size_t)e1 * 9 + 4 * q;
        float* o2 = out + (size_t)e2 * 9 + 4 * q;
#pragma unroll
        for (int i = 0; i < 4; ++i) {
            o1[i] = tanh_fast((float)a1[i] + (float)b1[i]);
            o2[i] = tanh_fast((float)a2[i] + (float)b2[i]);
        }
    } else {                                      // q == 2 -> element j = 8
        out[(size_t)e1 * 9 + 8] =
            tanh_fast((float)A[(size_t)r1 * 16 + 8] + (float)B[(size_t)c1 * 16 + 8]);
        out[(size_t)e2 * 9 + 8] =
            tanh_fast((float)A[(size_t)r2 * 16 + 8] + (float)B[(size_t)c2 * 16 + 8]);
    }
}

extern "C" void kernel_launch(void* const* d_in, const int* in_sizes, int n_in,
                              void* d_out, int out_size, void* d_ws, size_t ws_size,
                              hipStream_t stream) {
    const float* x  = (const float*)d_in[0];   // [N, 192] fp32
    const float* W  = (const float*)d_in[1];   // [9, 128] fp32
    const int*   ei = (const int*)d_in[2];     // [2, E] int32
    float* out = (float*)d_out;                // [E*9] fp32

    const int nnodes = in_sizes[0] / 192;
    const int nedges = in_sizes[2] / 2;

    _Float16* A = (_Float16*)d_ws;             // [nnodes*16] fp16 padded records
    _Float16* B = A + (size_t)nnodes * 16;     // [nnodes*16]

    const int blocks1 = (nnodes + 15) / 16;    // 16 nodes per 256-thread block
    node_proj_kernel<<<blocks1, 256, 0, stream>>>(x, W, A, B, nnodes);

    const int blocks2 = (nedges + 127) / 128;  // 128 edges per 256-thread block
    edge_map_kernel<<<blocks2, 256, 0, stream>>>(ei, A, B, out, nedges);
}

// Round 15
// 30.542 us; speedup vs baseline: 6.6437x; 1.2499x over previous
//
#include <hip/hip_runtime.h>
#include <cstddef>

// r15 = r12 (best verified: 30.15 us) with ONE change: kernel 2 processes
// 256 edges/block, FOUR edges per quad -> 8 independent record-gathers in
// flight per lane (the only k2 lever that has consistently won: MLP).
//
// out[e,j] = tanh( A[row[e],j] + B[col[e],j] )
// A[n] = W0·u + W1·v,  B[n] = W0·v + W1·u,  u = x[n,0:64]+x[n,128:192], v = x[n,64:128]
// Karatsuba: s=(W0+W1)/2·(u+v), d=(W0-W1)/2·(u-v) => A=s+d, B=s-d.
// A/B: fp16 records padded to 32B (16 halves). Tables 3.2 MB -> L2-resident.

typedef float v4f __attribute__((ext_vector_type(4)));
typedef _Float16 v4h __attribute__((ext_vector_type(4)));

__device__ __forceinline__ float tanh_fast(float s) {
    // tanh(s) = 1 - 2/(e^{2s}+1); exp via exp2. Inf/0 limits give +-1, no clamp.
    float ex = __builtin_amdgcn_exp2f(s * 2.88539008f);
    return fmaf(-2.0f, __builtin_amdgcn_rcpf(ex + 1.0f), 1.0f);
}

// Kernel 1 (r12, unchanged): per-node projections. 4 lanes per node; 64 nodes
// per 256-thread block; Karatsuba ws/wd in LDS; packed v4h stores.
__global__ __launch_bounds__(256) void node_proj_kernel(
    const float* __restrict__ x, const float* __restrict__ W,
    _Float16* __restrict__ A, _Float16* __restrict__ B, int nnodes)
{
    __shared__ float ws[9 * 64];   // (W0+W1)/2
    __shared__ float wd[9 * 64];   // (W0-W1)/2
    for (int k = threadIdx.x; k < 9 * 64; k += 256) {
        int j = k >> 6, c = k & 63;
        float w0 = W[j * 128 + c], w1 = W[j * 128 + 64 + c];
        ws[k] = 0.5f * (w0 + w1);
        wd[k] = 0.5f * (w0 - w1);
    }
    __syncthreads();

    const int quad = threadIdx.x >> 2;            // 0..63: node within block
    const int q    = threadIdx.x & 3;             // lane within quad
    const int n    = blockIdx.x * 64 + quad;
    if (n >= nnodes) return;

    const float* xr = x + (size_t)n * 192;

    float ps[9], pd[9];
#pragma unroll
    for (int j = 0; j < 9; ++j) { ps[j] = 0.0f; pd[j] = 0.0f; }

#pragma unroll
    for (int ii = 0; ii < 4; ++ii) {
        const int c = 16 * ii + 4 * q;            // this lane's float4 channel offset
        v4f x0 = *(const v4f*)(xr + c);
        v4f x1 = *(const v4f*)(xr + 64 + c);
        v4f x2 = *(const v4f*)(xr + 128 + c);
        v4f u = x0 + x2;                          // sum-pool halves
        v4f su = u + x1;                          // u + v
        v4f du = u - x1;                          // u - v
#pragma unroll
        for (int j = 0; j < 9; ++j) {
            v4f a = *(const v4f*)(ws + j * 64 + c);
            v4f b = *(const v4f*)(wd + j * 64 + c);
            ps[j] = fmaf(a.x, su.x, ps[j]); ps[j] = fmaf(a.y, su.y, ps[j]);
            ps[j] = fmaf(a.z, su.z, ps[j]); ps[j] = fmaf(a.w, su.w, ps[j]);
            pd[j] = fmaf(b.x, du.x, pd[j]); pd[j] = fmaf(b.y, du.y, pd[j]);
            pd[j] = fmaf(b.z, du.z, pd[j]); pd[j] = fmaf(b.w, du.w, pd[j]);
        }
    }

    // quad butterfly reduce: all 4 lanes end with full 64-channel sums
#pragma unroll
    for (int j = 0; j < 9; ++j) {
        ps[j] += __shfl_xor(ps[j], 1); ps[j] += __shfl_xor(ps[j], 2);
        pd[j] += __shfl_xor(pd[j], 1); pd[j] += __shfl_xor(pd[j], 2);
    }

    // Packed stores: lane q owns halves 4q..4q+3 (compile-time indices).
    v4h av, bv;
    if (q == 0) {
        av[0]=(_Float16)(ps[0]+pd[0]); bv[0]=(_Float16)(ps[0]-pd[0]);
        av[1]=(_Float16)(ps[1]+pd[1]); bv[1]=(_Float16)(ps[1]-pd[1]);
        av[2]=(_Float16)(ps[2]+pd[2]); bv[2]=(_Float16)(ps[2]-pd[2]);
        av[3]=(_Float16)(ps[3]+pd[3]); bv[3]=(_Float16)(ps[3]-pd[3]);
    } else if (q == 1) {
        av[0]=(_Float16)(ps[4]+pd[4]); bv[0]=(_Float16)(ps[4]-pd[4]);
        av[1]=(_Float16)(ps[5]+pd[5]); bv[1]=(_Float16)(ps[5]-pd[5]);
        av[2]=(_Float16)(ps[6]+pd[6]); bv[2]=(_Float16)(ps[6]-pd[6]);
        av[3]=(_Float16)(ps[7]+pd[7]); bv[3]=(_Float16)(ps[7]-pd[7]);
    } else if (q == 2) {
        av[0]=(_Float16)(ps[8]+pd[8]); bv[0]=(_Float16)(ps[8]-pd[8]);
        av[1]=av[2]=av[3]=(_Float16)0.0f; bv[1]=bv[2]=bv[3]=(_Float16)0.0f;
    } else {
        av[0]=av[1]=av[2]=av[3]=(_Float16)0.0f;
        bv[0]=bv[1]=bv[2]=bv[3]=(_Float16)0.0f;
    }
    *(v4h*)(A + (size_t)n * 16 + 4 * q) = av;     // coalesced 8B stores
    *(v4h*)(B + (size_t)n * 16 + 4 * q) = bv;
}

// Kernel 2: 256 edges per 256-thread block, FOUR edges per quad -> 8
// independent record gathers in flight per lane. Quad-cooperative 8B/lane
// gathers; LDS transpose; coalesced v4f stores.
__global__ __launch_bounds__(256) void edge_map_kernel(
    const int* __restrict__ ei, const _Float16* __restrict__ A,
    const _Float16* __restrict__ B, float* __restrict__ out, int nedges)
{
    __shared__ float so[256 * 9];                 // 9 KB
    const int quad = threadIdx.x >> 2;            // 0..63
    const int q    = threadIdx.x & 3;             // lane within quad
    const int e0   = blockIdx.x * 256;

    if (q < 3) {                                  // q==3: pad halves only
        const int e1 = min(e0 + quad,       nedges - 1);   // clamped, safe
        const int e2 = min(e0 + 64 + quad,  nedges - 1);
        const int e3 = min(e0 + 128 + quad, nedges - 1);
        const int e4 = min(e0 + 192 + quad, nedges - 1);
        int r1 = ei[e1], c1 = ei[nedges + e1];    // quad-broadcast loads
        int r2 = ei[e2], c2 = ei[nedges + e2];
        int r3 = ei[e3], c3 = ei[nedges + e3];
        int r4 = ei[e4], c4 = ei[nedges + e4];
        v4h a1 = *(const v4h*)(A + (size_t)r1 * 16 + 4 * q);
        v4h b1 = *(const v4h*)(B + (size_t)c1 * 16 + 4 * q);
        v4h a2 = *(const v4h*)(A + (size_t)r2 * 16 + 4 * q);
        v4h b2 = *(const v4h*)(B + (size_t)c2 * 16 + 4 * q);
        v4h a3 = *(const v4h*)(A + (size_t)r3 * 16 + 4 * q);
        v4h b3 = *(const v4h*)(B + (size_t)c3 * 16 + 4 * q);
        v4h a4 = *(const v4h*)(A + (size_t)r4 * 16 + 4 * q);
        v4h b4 = *(const v4h*)(B + (size_t)c4 * 16 + 4 * q);
        float* s1 = so + quad * 9 + 4 * q;
        float* s2 = so + (quad + 64) * 9 + 4 * q;
        float* s3 = so + (quad + 128) * 9 + 4 * q;
        float* s4 = so + (quad + 192) * 9 + 4 * q;
#pragma unroll
        for (int i = 0; i < 4; ++i) {
            if (4 * q + i < 9) {                  // q<2: all 4; q==2: only i==0
                s1[i] = tanh_fast((float)a1[i] + (float)b1[i]);
                s2[i] = tanh_fast((float)a2[i] + (float)b2[i]);
                s3[i] = tanh_fast((float)a3[i] + (float)b3[i]);
                s4[i] = tanh_fast((float)a4[i] + (float)b4[i]);
            }
        }
    }
    __syncthreads();

    const int nval = min(256, nedges - e0) * 9;   // 2304 for full blocks
    float* ob = out + (size_t)e0 * 9;
    for (int k4 = threadIdx.x * 4; k4 < nval; k4 += 1024) {
        if (k4 + 4 <= nval) {
            *(v4f*)(ob + k4) = *(const v4f*)(so + k4);   // coalesced
        } else {
            for (int m = k4; m < nval; ++m) ob[m] = so[m];
        }
    }
}

extern "C" void kernel_launch(void* const* d_in, const int* in_sizes, int n_in,
                              void* d_out, int out_size, void* d_ws, size_t ws_size,
                              hipStream_t stream) {
    const float* x  = (const float*)d_in[0];   // [N, 192] fp32
    const float* W  = (const float*)d_in[1];   // [9, 128] fp32
    const int*   ei = (const int*)d_in[2];     // [2, E] int32
    float* out = (float*)d_out;                // [E*9] fp32

    const int nnodes = in_sizes[0] / 192;
    const int nedges = in_sizes[2] / 2;

    _Float16* A = (_Float16*)d_ws;             // [nnodes*16] fp16 padded records
    _Float16* B = A + (size_t)nnodes * 16;     // [nnodes*16]

    const int blocks1 = (nnodes + 63) / 64;
    node_proj_kernel<<<blocks1, 256, 0, stream>>>(x, W, A, B, nnodes);

    const int blocks2 = (nedges + 255) / 256;  // 256 edges per 256-thread block
    edge_map_kernel<<<blocks2, 256, 0, stream>>>(ei, A, B, out, nedges);
}

// Round 16
// 30.456 us; speedup vs baseline: 6.6626x; 1.0028x over previous
//
#include <hip/hip_runtime.h>
#include <cstddef>

// FINAL (= round-12 best verified: 30.15 us).
// out[e,j] = tanh( A[row[e],j] + B[col[e],j] )
// A[n] = W0·u + W1·v,  B[n] = W0·v + W1·u,  u = x[n,0:64]+x[n,128:192], v = x[n,64:128]
// Karatsuba: s=(W0+W1)/2·(u+v), d=(W0-W1)/2·(u-v) => A=s+d, B=s-d.
// A/B: fp16 records padded to 32B (16 halves); tables 3.2 MB -> L2-resident.
// k1: 4 lanes/node, ws/wd in LDS, quad butterfly reduce, packed v4h stores.
// k2: 128 edges/block, 2 edges/quad (4 gathers in flight/lane — measured MLP
//     optimum), quad-cooperative 8B/lane gathers, LDS transpose, v4f stores.

typedef float v4f __attribute__((ext_vector_type(4)));
typedef _Float16 v4h __attribute__((ext_vector_type(4)));

__device__ __forceinline__ float tanh_fast(float s) {
    // tanh(s) = 1 - 2/(e^{2s}+1); exp via exp2. Inf/0 limits give +-1, no clamp.
    float ex = __builtin_amdgcn_exp2f(s * 2.88539008f);
    return fmaf(-2.0f, __builtin_amdgcn_rcpf(ex + 1.0f), 1.0f);
}

// Kernel 1: per-node projections. 4 lanes (a quad) per node; 64 nodes per 256-thread block.
__global__ __launch_bounds__(256) void node_proj_kernel(
    const float* __restrict__ x, const float* __restrict__ W,
    _Float16* __restrict__ A, _Float16* __restrict__ B, int nnodes)
{
    __shared__ float ws[9 * 64];   // (W0+W1)/2
    __shared__ float wd[9 * 64];   // (W0-W1)/2
    for (int k = threadIdx.x; k < 9 * 64; k += 256) {
        int j = k >> 6, c = k & 63;
        float w0 = W[j * 128 + c], w1 = W[j * 128 + 64 + c];
        ws[k] = 0.5f * (w0 + w1);
        wd[k] = 0.5f * (w0 - w1);
    }
    __syncthreads();

    const int quad = threadIdx.x >> 2;            // 0..63: node within block
    const int q    = threadIdx.x & 3;             // lane within quad
    const int n    = blockIdx.x * 64 + quad;
    if (n >= nnodes) return;

    const float* xr = x + (size_t)n * 192;

    float ps[9], pd[9];
#pragma unroll
    for (int j = 0; j < 9; ++j) { ps[j] = 0.0f; pd[j] = 0.0f; }

#pragma unroll
    for (int ii = 0; ii < 4; ++ii) {
        const int c = 16 * ii + 4 * q;            // this lane's float4 channel offset
        v4f x0 = *(const v4f*)(xr + c);
        v4f x1 = *(const v4f*)(xr + 64 + c);
        v4f x2 = *(const v4f*)(xr + 128 + c);
        v4f u = x0 + x2;                          // sum-pool halves
        v4f su = u + x1;                          // u + v
        v4f du = u - x1;                          // u - v
#pragma unroll
        for (int j = 0; j < 9; ++j) {
            v4f a = *(const v4f*)(ws + j * 64 + c);
            v4f b = *(const v4f*)(wd + j * 64 + c);
            ps[j] = fmaf(a.x, su.x, ps[j]); ps[j] = fmaf(a.y, su.y, ps[j]);
            ps[j] = fmaf(a.z, su.z, ps[j]); ps[j] = fmaf(a.w, su.w, ps[j]);
            pd[j] = fmaf(b.x, du.x, pd[j]); pd[j] = fmaf(b.y, du.y, pd[j]);
            pd[j] = fmaf(b.z, du.z, pd[j]); pd[j] = fmaf(b.w, du.w, pd[j]);
        }
    }

    // quad butterfly reduce: all 4 lanes end with full 64-channel sums
#pragma unroll
    for (int j = 0; j < 9; ++j) {
        ps[j] += __shfl_xor(ps[j], 1); ps[j] += __shfl_xor(ps[j], 2);
        pd[j] += __shfl_xor(pd[j], 1); pd[j] += __shfl_xor(pd[j], 2);
    }

    // Packed stores: lane q owns halves 4q..4q+3 (compile-time indices).
    v4h av, bv;
    if (q == 0) {
        av[0]=(_Float16)(ps[0]+pd[0]); bv[0]=(_Float16)(ps[0]-pd[0]);
        av[1]=(_Float16)(ps[1]+pd[1]); bv[1]=(_Float16)(ps[1]-pd[1]);
        av[2]=(_Float16)(ps[2]+pd[2]); bv[2]=(_Float16)(ps[2]-pd[2]);
        av[3]=(_Float16)(ps[3]+pd[3]); bv[3]=(_Float16)(ps[3]-pd[3]);
    } else if (q == 1) {
        av[0]=(_Float16)(ps[4]+pd[4]); bv[0]=(_Float16)(ps[4]-pd[4]);
        av[1]=(_Float16)(ps[5]+pd[5]); bv[1]=(_Float16)(ps[5]-pd[5]);
        av[2]=(_Float16)(ps[6]+pd[6]); bv[2]=(_Float16)(ps[6]-pd[6]);
        av[3]=(_Float16)(ps[7]+pd[7]); bv[3]=(_Float16)(ps[7]-pd[7]);
    } else if (q == 2) {
        av[0]=(_Float16)(ps[8]+pd[8]); bv[0]=(_Float16)(ps[8]-pd[8]);
        av[1]=av[2]=av[3]=(_Float16)0.0f; bv[1]=bv[2]=bv[3]=(_Float16)0.0f;
    } else {
        av[0]=av[1]=av[2]=av[3]=(_Float16)0.0f;
        bv[0]=bv[1]=bv[2]=bv[3]=(_Float16)0.0f;
    }
    *(v4h*)(A + (size_t)n * 16 + 4 * q) = av;     // coalesced 8B stores
    *(v4h*)(B + (size_t)n * 16 + 4 * q) = bv;
}

// Kernel 2: 128 edges per 256-thread block, TWO edges per quad -> 4 independent
// record gathers in flight per lane. Quad-cooperative 8B-per-lane gathers of the
// 32B records; LDS transpose; coalesced v4f stores.
__global__ __launch_bounds__(256) void edge_map_kernel(
    const int* __restrict__ ei, const _Float16* __restrict__ A,
    const _Float16* __restrict__ B, float* __restrict__ out, int nedges)
{
    __shared__ float so[128 * 9];                 // 4.5 KB
    const int quad = threadIdx.x >> 2;            // 0..63
    const int q    = threadIdx.x & 3;             // lane within quad
    const int e0   = blockIdx.x * 128;

    if (q < 3) {                                  // q==3: pad halves only
        const int e1 = min(e0 + quad,      nedges - 1);   // clamped, always safe
        const int e2 = min(e0 + 64 + quad, nedges - 1);
        int r1 = ei[e1], c1 = ei[nedges + e1];    // quad-broadcast loads
        int r2 = ei[e2], c2 = ei[nedges + e2];
        v4h a1 = *(const v4h*)(A + (size_t)r1 * 16 + 4 * q);
        v4h b1 = *(const v4h*)(B + (size_t)c1 * 16 + 4 * q);
        v4h a2 = *(const v4h*)(A + (size_t)r2 * 16 + 4 * q);
        v4h b2 = *(const v4h*)(B + (size_t)c2 * 16 + 4 * q);
        float* s1 = so + quad * 9 + 4 * q;
        float* s2 = so + (quad + 64) * 9 + 4 * q;
#pragma unroll
        for (int i = 0; i < 4; ++i) {
            if (4 * q + i < 9) {                  // q<2: all 4; q==2: only i==0
                s1[i] = tanh_fast((float)a1[i] + (float)b1[i]);
                s2[i] = tanh_fast((float)a2[i] + (float)b2[i]);
            }
        }
    }
    __syncthreads();

    const int nval = min(128, nedges - e0) * 9;   // 1152 for full blocks
    float* ob = out + (size_t)e0 * 9;
    for (int k4 = threadIdx.x * 4; k4 < nval; k4 += 1024) {
        if (k4 + 4 <= nval) {
            *(v4f*)(ob + k4) = *(const v4f*)(so + k4);   // coalesced
        } else {
            for (int m = k4; m < nval; ++m) ob[m] = so[m];
        }
    }
}

extern "C" void kernel_launch(void* const* d_in, const int* in_sizes, int n_in,
                              void* d_out, int out_size, void* d_ws, size_t ws_size,
                              hipStream_t stream) {
    const float* x  = (const float*)d_in[0];   // [N, 192] fp32
    const float* W  = (const float*)d_in[1];   // [9, 128] fp32
    const int*   ei = (const int*)d_in[2];     // [2, E] int32
    float* out = (float*)d_out;                // [E*9] fp32

    const int nnodes = in_sizes[0] / 192;
    const int nedges = in_sizes[2] / 2;

    _Float16* A = (_Float16*)d_ws;             // [nnodes*16] fp16 padded records
    _Float16* B = A + (size_t)nnodes * 16;     // [nnodes*16]

    const int blocks1 = (nnodes + 63) / 64;
    node_proj_kernel<<<blocks1, 256, 0, stream>>>(x, W, A, B, nnodes);

    const int blocks2 = (nedges + 127) / 128;  // 128 edges per 256-thread block
    edge_map_kernel<<<blocks2, 256, 0, stream>>>(ei, A, B, out, nedges);
}